// Round 3
// baseline (286.584 us; speedup 1.0000x reference)
//
#include <hip/hip_runtime.h>

// GaussianSplatting preprocess, fully-coalesced version.
//   out = concat(positions [N,3], cov [N,3,3], alphas [N], sh [N,4]) flat f32
//   cov = (R S)(R S)^T
// Strategy: per-block LDS staging so every global load/store is a coalesced
// 16B vector op. Non-temporal stores keep outputs from evicting L3 inputs.
// NOTE: __builtin_nontemporal_store needs a clang native vector type, not
// HIP's float4 class — use ext_vector_type(4).

typedef float v4f __attribute__((ext_vector_type(4)));

#define SH_C0 0.282095f
#define SH_C1 0.488603f
#define BLK 256

__global__ __launch_bounds__(BLK) void gs_kernel(
    const float* __restrict__ pos,
    const float* __restrict__ col,
    const float* __restrict__ alp,
    const float* __restrict__ Rm,
    const float* __restrict__ Sm,
    float* __restrict__ out_pos,   // [n*3]
    float* __restrict__ out_cov,   // [n*9]
    float* __restrict__ out_alp,   // [n]
    float* __restrict__ out_sh,    // [n*4]
    int n)
{
    __shared__ float ldsR[BLK * 9];   // 9216 B — reused for cov output
    __shared__ float ldsS[BLK * 9];   // 9216 B
    __shared__ float ldsC[BLK * 3];   // 3072 B

    const int t  = threadIdx.x;
    const int b  = blockIdx.x;
    const int p0 = b * BLK;
    const int cnt = min(BLK, n - p0);          // points in this block

    // ---- Phase A: coalesced v4f loads into LDS ----
    const int nrs4 = (cnt * 9) / 4;
    const int nc4  = (cnt * 3) / 4;
    const v4f* Rv = (const v4f*)(Rm + (size_t)p0 * 9);
    const v4f* Sv = (const v4f*)(Sm + (size_t)p0 * 9);
    const v4f* Cv = (const v4f*)(col + (size_t)p0 * 3);
    v4f* ldsRv = (v4f*)ldsR;
    v4f* ldsSv = (v4f*)ldsS;
    v4f* ldsCv = (v4f*)ldsC;
    for (int k = t; k < nrs4; k += BLK) {
        ldsRv[k] = Rv[k];
        ldsSv[k] = Sv[k];
    }
    for (int k = t; k < nc4; k += BLK) ldsCv[k] = Cv[k];
    // scalar tails (cnt%4!=0 only possible on the last block)
    for (int k = nrs4 * 4 + t; k < cnt * 9; k += BLK) {
        ldsR[k] = Rm[(size_t)p0 * 9 + k];
        ldsS[k] = Sm[(size_t)p0 * 9 + k];
    }
    for (int k = nc4 * 4 + t; k < cnt * 3; k += BLK)
        ldsC[k] = col[(size_t)p0 * 3 + k];
    __syncthreads();

    // ---- Phase B: per-thread 3x3 compute from LDS ----
    float covv[9];
    const bool active = (t < cnt);
    if (active) {
        float r[9], s[9], tt[9];
#pragma unroll
        for (int k = 0; k < 9; ++k) r[k] = ldsR[9 * t + k];
#pragma unroll
        for (int k = 0; k < 9; ++k) s[k] = ldsS[9 * t + k];
#pragma unroll
        for (int a = 0; a < 3; ++a)
#pragma unroll
            for (int c = 0; c < 3; ++c)
                tt[3 * a + c] = r[3 * a + 0] * s[0 + c]
                              + r[3 * a + 1] * s[3 + c]
                              + r[3 * a + 2] * s[6 + c];
#pragma unroll
        for (int a = 0; a < 3; ++a)
#pragma unroll
            for (int c = 0; c < 3; ++c)
                covv[3 * a + c] = tt[3 * a + 0] * tt[3 * c + 0]
                                + tt[3 * a + 1] * tt[3 * c + 1]
                                + tt[3 * a + 2] * tt[3 * c + 2];

        // sh: aligned v4f store directly (16B-aligned at 4*(p0+t))
        float c0 = ldsC[3 * t + 0], c1 = ldsC[3 * t + 1], c2 = ldsC[3 * t + 2];
        v4f sh = {SH_C0, c1 * SH_C1, c0 * SH_C1, c2 * SH_C1};
        __builtin_nontemporal_store(sh, (v4f*)(out_sh + (size_t)(p0 + t) * 4));
    }

    // ---- Phase B2: stage cov into LDS (reuse R buffer) ----
    __syncthreads();   // everyone done reading ldsR before overwrite
    if (active) {
#pragma unroll
        for (int k = 0; k < 9; ++k) ldsR[9 * t + k] = covv[k];
    }
    __syncthreads();

    // ---- Phase C: coalesced v4f cov store ----
    v4f* Ov = (v4f*)(out_cov + (size_t)p0 * 9);
    for (int k = t; k < nrs4; k += BLK)
        __builtin_nontemporal_store(ldsRv[k], Ov + k);
    for (int k = nrs4 * 4 + t; k < cnt * 9; k += BLK)
        out_cov[(size_t)p0 * 9 + k] = ldsR[k];

    // ---- Phase D: pos + alpha v4f copies ----
    {
        const int np4 = (cnt * 3) / 4;
        const v4f* Pv = (const v4f*)(pos + (size_t)p0 * 3);
        v4f*      OPv = (v4f*)(out_pos + (size_t)p0 * 3);
        for (int k = t; k < np4; k += BLK)
            __builtin_nontemporal_store(Pv[k], OPv + k);
        for (int k = np4 * 4 + t; k < cnt * 3; k += BLK)
            out_pos[(size_t)p0 * 3 + k] = pos[(size_t)p0 * 3 + k];

        const int na4 = cnt / 4;
        const v4f* Av = (const v4f*)(alp + (size_t)p0);
        v4f*      OAv = (v4f*)(out_alp + (size_t)p0);
        for (int k = t; k < na4; k += BLK)
            __builtin_nontemporal_store(Av[k], OAv + k);
        for (int k = na4 * 4 + t; k < cnt; k += BLK)
            out_alp[(size_t)p0 + k] = alp[(size_t)p0 + k];
    }
}

extern "C" void kernel_launch(void* const* d_in, const int* in_sizes, int n_in,
                              void* d_out, int out_size, void* d_ws, size_t ws_size,
                              hipStream_t stream) {
    const float* pos = (const float*)d_in[0];  // [N,3]
    const float* col = (const float*)d_in[1];  // [N,3]
    const float* alp = (const float*)d_in[2];  // [N]
    const float* Rm  = (const float*)d_in[3];  // [N,3,3]
    const float* Sm  = (const float*)d_in[4];  // [N,3,3]

    int n = in_sizes[0] / 3;

    float* out = (float*)d_out;
    float* out_pos = out;                     // n*3
    float* out_cov = out + (size_t)3 * n;     // n*9
    float* out_alp = out + (size_t)12 * n;    // n
    float* out_sh  = out + (size_t)13 * n;    // n*4

    int grid = (n + BLK - 1) / BLK;
    gs_kernel<<<grid, BLK, 0, stream>>>(pos, col, alp, Rm, Sm,
                                        out_pos, out_cov, out_alp, out_sh, n);
}